// Round 1
// baseline (317.739 us; speedup 1.0000x reference)
//
#include <hip/hip_runtime.h>
#include <stdint.h>

#define D_MODEL 1024
#define NHEADS  16
#define DEPTH   64
#define BATCH   2
#define SEQ     2048
#define M_TOK   (BATCH*SEQ)   // 4096

typedef __attribute__((ext_vector_type(8))) short short8;
typedef __attribute__((ext_vector_type(4))) float f32x4;

__device__ __forceinline__ unsigned short f2bf(float f) {
  unsigned int u = __float_as_uint(f);
  u += 0x7fffu + ((u >> 16) & 1u);
  return (unsigned short)(u >> 16);
}

__device__ __forceinline__ void gload_lds16(const unsigned short* g, unsigned short* l) {
  __builtin_amdgcn_global_load_lds((const __attribute__((address_space(1))) void*)g,
                                   (__attribute__((address_space(3))) void*)l, 16, 0, 0);
}

// ---------------- fp32 -> bf16 elementwise (x) ----------------
__global__ void mha_cvt_bf16(const float* __restrict__ in, unsigned short* __restrict__ out) {
  int i = (blockIdx.x * 256 + threadIdx.x) * 8;
  float4 a = *(const float4*)(in + i);
  float4 b = *(const float4*)(in + i + 4);
  uint4 r;
  r.x = (unsigned)f2bf(a.x) | ((unsigned)f2bf(a.y) << 16);
  r.y = (unsigned)f2bf(a.z) | ((unsigned)f2bf(a.w) << 16);
  r.z = (unsigned)f2bf(b.x) | ((unsigned)f2bf(b.y) << 16);
  r.w = (unsigned)f2bf(b.z) | ((unsigned)f2bf(b.w) << 16);
  *(uint4*)(out + i) = r;
}

// ------- Wqkv [1024][3072] -> permuted transposed bf16 --------
// col c = (h*64+d)*3 + s.  s<2 -> wqkT[(s*1024 + h*64+d)][k]; s==2 -> wvT[(h*64+d)][k]
__global__ void mha_perm_wqkv(const float* __restrict__ W,
                              unsigned short* __restrict__ wqkT,
                              unsigned short* __restrict__ wvT) {
  __shared__ float tile[32][33];
  int c0 = blockIdx.x * 32, k0 = blockIdx.y * 32;
  int tx = threadIdx.x, ty = threadIdx.y;
  for (int i = ty; i < 32; i += 8)
    tile[i][tx] = W[(size_t)(k0 + i) * 3072 + c0 + tx];
  __syncthreads();
  for (int i = ty; i < 32; i += 8) {
    int c = c0 + i;
    int hd = c / 3;
    int s = c - hd * 3;
    unsigned short v = f2bf(tile[tx][i]);
    if (s < 2) wqkT[(size_t)(s * 1024 + hd) * 1024 + k0 + tx] = v;
    else       wvT [(size_t)hd * 1024 + k0 + tx] = v;
  }
}

// ------- Wproj [1024][1024] -> transposed bf16 [c][k] --------
__global__ void mha_t_wproj(const float* __restrict__ W, unsigned short* __restrict__ wpT) {
  __shared__ float tile[32][33];
  int c0 = blockIdx.x * 32, k0 = blockIdx.y * 32;
  int tx = threadIdx.x, ty = threadIdx.y;
  for (int i = ty; i < 32; i += 8)
    tile[i][tx] = W[(size_t)(k0 + i) * 1024 + c0 + tx];
  __syncthreads();
  for (int i = ty; i < 32; i += 8)
    wpT[(size_t)(c0 + i) * 1024 + k0 + tx] = f2bf(tile[tx][i]);
}

// ---------------- 128x128 bf16 gemm_bt (m97-style) ----------------
// C[M][N] = A[M][K=1024] @ Bt[N][K=1024]^T  (+ per-mode epilogue)
// MODE 0: QK-part.  cols c'= s*1024+h*64+d; write bf16 Q (scaled 1/8) / K as [bh][n][64]
// MODE 1: V-part.   A=wvT rows hd, Bt=x_b (per blockIdx.z); write bf16 Vt as [bh][d][n]
// MODE 2: proj.     write fp32 to d_out
template<int MODE>
__global__ __launch_bounds__(256, 2) void mha_gemm_bt(
    const unsigned short* __restrict__ A,
    const unsigned short* __restrict__ Bt,
    const float* __restrict__ bias,
    unsigned short* __restrict__ out_a,
    unsigned short* __restrict__ out_b,
    float* __restrict__ out_f)
{
  __shared__ __align__(16) unsigned short As[128 * 32];
  __shared__ __align__(16) unsigned short Bs[128 * 32];
  const int K = 1024;
  int t = threadIdx.x;
  int wv = t >> 6, lane = t & 63;
  int l15 = lane & 15, l4 = lane >> 4;
  int wr = wv >> 1, wc = wv & 1;
  int blkM = blockIdx.y * 128, blkN = blockIdx.x * 128;
  if (MODE == 1) Bt += (size_t)blockIdx.z * SEQ * D_MODEL;

  f32x4 acc[4][4];
  for (int m = 0; m < 4; m++) for (int n = 0; n < 4; n++) acc[m][n] = (f32x4){0.f,0.f,0.f,0.f};

  int srow = t >> 2;              // staging row within 128 (chunk 0)
  int skc  = (t & 3) * 8;         // staging k offset
  for (int kt = 0; kt < K; kt += 32) {
    #pragma unroll
    for (int i = 0; i < 2; i++) {
      int e = i * 256 + t;
      int row = srow + i * 64;
      gload_lds16(A  + (size_t)(blkM + row) * K + kt + skc, As + e * 8);
      gload_lds16(Bt + (size_t)(blkN + row) * K + kt + skc, Bs + e * 8);
    }
    __syncthreads();
    short8 af[4], bf[4];
    #pragma unroll
    for (int m = 0; m < 4; m++)
      af[m] = *(const short8*)&As[(wr * 64 + m * 16 + l15) * 32 + l4 * 8];
    #pragma unroll
    for (int n = 0; n < 4; n++)
      bf[n] = *(const short8*)&Bs[(wc * 64 + n * 16 + l15) * 32 + l4 * 8];
    #pragma unroll
    for (int m = 0; m < 4; m++)
      #pragma unroll
      for (int n = 0; n < 4; n++)
        acc[m][n] = __builtin_amdgcn_mfma_f32_16x16x32_bf16(af[m], bf[n], acc[m][n], 0, 0, 0);
    __syncthreads();
  }

  int row0 = blkM + wr * 64;
  int col0 = blkN + wc * 64;
  #pragma unroll
  for (int m = 0; m < 4; m++) {
    #pragma unroll
    for (int n = 0; n < 4; n++) {
      int colb = col0 + n * 16 + l15;
      #pragma unroll
      for (int j = 0; j < 4; j++) {
        int row = row0 + m * 16 + l4 * 4 + j;
        float v = acc[m][n][j];
        if (MODE == 0) {
          int s = colb >> 10, hd = colb & 1023;
          v += bias[hd * 3 + s];
          if (s == 0) v *= 0.125f;   // fold softmax scale into Q (exact pow2)
          size_t idx = ((size_t)((row >> 11) * NHEADS + (hd >> 6)) * SEQ + (row & 2047)) * DEPTH + (hd & 63);
          (s == 0 ? out_a : out_b)[idx] = f2bf(v);
        } else if (MODE == 1) {
          v += bias[row * 3 + 2];
          out_a[((size_t)(blockIdx.z * 1024 + row)) * SEQ + colb] = f2bf(v);
        } else {
          v += bias[colb];
          out_f[(size_t)row * D_MODEL + colb] = v;
        }
      }
    }
  }
}

// ---------------- flash attention ----------------
// Q [32][2048][64] bf16 (pre-scaled), K [32][2048][64] bf16, Vt [32][64][2048] bf16
// O  [B][2048][1024] bf16 ([b][n][h*64+d])
__global__ __launch_bounds__(256, 2) void mha_attn(
    const unsigned short* __restrict__ Q,
    const unsigned short* __restrict__ Kb,
    const unsigned short* __restrict__ Vt,
    unsigned short* __restrict__ O)
{
  const int N = SEQ;
  int bh = blockIdx.y;      // 0..31
  int qblk = blockIdx.x;    // 0..31
  int t = threadIdx.x, wv = t >> 6, lane = t & 63;
  int l15 = lane & 15, l4 = lane >> 4;

  __shared__ __align__(16) unsigned short Ps[4][16][88];   // pad 88 -> 2-way banks, 16B aligned

  const unsigned short* Qb  = Q  + ((size_t)bh * N + qblk * 64 + wv * 16) * DEPTH;
  const unsigned short* Kbh = Kb + (size_t)bh * N * DEPTH;
  const unsigned short* Vbh = Vt + (size_t)bh * DEPTH * N;

  short8 qf[2];
  qf[0] = *(const short8*)&Qb[(size_t)l15 * DEPTH + l4 * 8];
  qf[1] = *(const short8*)&Qb[(size_t)l15 * DEPTH + 32 + l4 * 8];

  float m_run[4], l_run[4];
  f32x4 oacc[4];
  #pragma unroll
  for (int j = 0; j < 4; j++) { m_run[j] = -1e30f; l_run[j] = 0.f; }
  #pragma unroll
  for (int d = 0; d < 4; d++) oacc[d] = (f32x4){0.f,0.f,0.f,0.f};

  for (int kt = 0; kt < N; kt += 64) {
    // ---- S = Q K^T for this 16x64 strip ----
    f32x4 sc[4];
    #pragma unroll
    for (int ct = 0; ct < 4; ct++) {
      const unsigned short* kp = Kbh + (size_t)(kt + ct * 16 + l15) * DEPTH + l4 * 8;
      short8 kf0 = *(const short8*)kp;
      short8 kf1 = *(const short8*)(kp + 32);
      f32x4 z = (f32x4){0.f,0.f,0.f,0.f};
      z = __builtin_amdgcn_mfma_f32_16x16x32_bf16(qf[0], kf0, z, 0, 0, 0);
      z = __builtin_amdgcn_mfma_f32_16x16x32_bf16(qf[1], kf1, z, 0, 0, 0);
      sc[ct] = z;
    }
    // ---- online softmax ----
    float mnew[4], corr[4];
    #pragma unroll
    for (int j = 0; j < 4; j++) {
      float mx = fmaxf(fmaxf(sc[0][j], sc[1][j]), fmaxf(sc[2][j], sc[3][j]));
      mx = fmaxf(mx, __shfl_xor(mx, 1));
      mx = fmaxf(mx, __shfl_xor(mx, 2));
      mx = fmaxf(mx, __shfl_xor(mx, 4));
      mx = fmaxf(mx, __shfl_xor(mx, 8));
      mnew[j] = fmaxf(m_run[j], mx);
      corr[j] = __expf(m_run[j] - mnew[j]);
      m_run[j] = mnew[j];
    }
    #pragma unroll
    for (int j = 0; j < 4; j++) {
      float sum = 0.f;
      #pragma unroll
      for (int ct = 0; ct < 4; ct++) {
        float p = __expf(sc[ct][j] - mnew[j]);
        sum += p;
        Ps[wv][l4 * 4 + j][ct * 16 + l15] = f2bf(p);
      }
      sum += __shfl_xor(sum, 1);
      sum += __shfl_xor(sum, 2);
      sum += __shfl_xor(sum, 4);
      sum += __shfl_xor(sum, 8);
      l_run[j] = l_run[j] * corr[j] + sum;
    }
    #pragma unroll
    for (int d = 0; d < 4; d++)
      #pragma unroll
      for (int j = 0; j < 4; j++) oacc[d][j] *= corr[j];
    // ---- PV ----
    short8 pf[2];
    pf[0] = *(const short8*)&Ps[wv][l15][l4 * 8];
    pf[1] = *(const short8*)&Ps[wv][l15][32 + l4 * 8];
    #pragma unroll
    for (int dt = 0; dt < 4; dt++) {
      const unsigned short* vp = Vbh + (size_t)(dt * 16 + l15) * N + kt + l4 * 8;
      short8 vf0 = *(const short8*)vp;
      short8 vf1 = *(const short8*)(vp + 32);
      oacc[dt] = __builtin_amdgcn_mfma_f32_16x16x32_bf16(pf[0], vf0, oacc[dt], 0, 0, 0);
      oacc[dt] = __builtin_amdgcn_mfma_f32_16x16x32_bf16(pf[1], vf1, oacc[dt], 0, 0, 0);
    }
  }

  int b = bh >> 4, h = bh & 15;
  #pragma unroll
  for (int dt = 0; dt < 4; dt++)
    #pragma unroll
    for (int j = 0; j < 4; j++) {
      int row = qblk * 64 + wv * 16 + l4 * 4 + j;
      float v = oacc[dt][j] / l_run[j];
      O[((size_t)b * N + row) * D_MODEL + h * DEPTH + dt * 16 + l15] = f2bf(v);
    }
}

extern "C" void kernel_launch(void* const* d_in, const int* in_sizes, int n_in,
                              void* d_out, int out_size, void* d_ws, size_t ws_size,
                              hipStream_t stream) {
  const float* x     = (const float*)d_in[0];
  const float* Wqkv  = (const float*)d_in[1];
  const float* bqkv  = (const float*)d_in[2];
  const float* Wproj = (const float*)d_in[3];
  const float* bproj = (const float*)d_in[4];
  float* out = (float*)d_out;

  char* w = (char*)d_ws;
  unsigned short* xb    = (unsigned short*)(w);                       // 8 MB
  unsigned short* wqkT  = (unsigned short*)(w + 8388608);             // 4 MB
  unsigned short* wvT   = (unsigned short*)(w + 8388608 + 4194304);   // 2 MB
  unsigned short* wpT   = (unsigned short*)(w + 8388608 + 4194304 + 2097152);  // 2 MB
  unsigned short* Qbuf  = (unsigned short*)(w + 16777216);            // 8 MB
  unsigned short* Kbuf  = (unsigned short*)(w + 16777216 + 8388608);  // 8 MB
  unsigned short* Vtb   = (unsigned short*)(w + 16777216 + 16777216); // 8 MB
  unsigned short* AOut  = (unsigned short*)(w + 16777216 + 25165824); // 8 MB

  // 1. x -> bf16
  mha_cvt_bf16<<<M_TOK * D_MODEL / (256 * 8), 256, 0, stream>>>(x, xb);
  // 2. Wqkv -> permuted transposed bf16 (QK part + V part)
  mha_perm_wqkv<<<dim3(96, 32), dim3(32, 8), 0, stream>>>(Wqkv, wqkT, wvT);
  // 3. Wproj -> transposed bf16
  mha_t_wproj<<<dim3(32, 32), dim3(32, 8), 0, stream>>>(Wproj, wpT);
  // 4. QK gemm: [4096 x 2048]
  mha_gemm_bt<0><<<dim3(16, 32), 256, 0, stream>>>(xb, wqkT, bqkv, Qbuf, Kbuf, nullptr);
  // 5. V gemm (transposed output): per batch [1024 x 2048]
  mha_gemm_bt<1><<<dim3(16, 8, 2), 256, 0, stream>>>(wvT, xb, bqkv, Vtb, nullptr, nullptr);
  // 6. flash attention
  mha_attn<<<dim3(32, 32), 256, 0, stream>>>(Qbuf, Kbuf, Vtb, AOut);
  // 7. projection gemm -> fp32 out
  mha_gemm_bt<2><<<dim3(8, 32), 256, 0, stream>>>(AOut, wpT, bproj, nullptr, nullptr, out);
}